// Round 4
// baseline (137.290 us; speedup 1.0000x reference)
//
#include <hip/hip_runtime.h>
#include <hip/hip_bf16.h>
#include <math.h>

#define BB 16
#define CC 128
#define NN 2048
#define CQ 32   // C/4

typedef __attribute__((ext_vector_type(8))) short bf16x8;
typedef __attribute__((ext_vector_type(4))) float f32x4;
typedef __attribute__((ext_vector_type(16))) float f32x16;

__device__ __forceinline__ ushort f2b(float f) {
    __hip_bfloat16 h = __float2bfloat16(f);
    return *reinterpret_cast<ushort*>(&h);
}
__device__ __forceinline__ float b2f(ushort u) {
    union { unsigned u; float f; } v; v.u = ((unsigned)u) << 16;
    return v.f;
}
__device__ __forceinline__ bf16x8 as_b8(uint4 u) {
    union { uint4 u; bf16x8 b; } v; v.u = u; return v.b;
}

// ---------------- workspace layout (float granularity offsets) ----------------
// Qt  : bf16 [B][N][32]   off 0          (524,288 fl)
// Vb  : bf16 [B][128][N]  off 524,288    (2,097,152 fl)
// XRb : bf16 [B][128][N]  off 2,621,440  (2,097,152 fl)
// RSI : f32  [B][N]       off 4,718,592  (32,768 fl)
// WQV : bf16 [160][128]   off 4,751,360  (10,240 fl)
// WTB : bf16 [128][128]   off 4,761,600  (8,192 fl)
// FA  : f32  [128]        off 4,769,792
// FB  : f32  [128]        off 4,769,920
#define OFF_VB  524288
#define OFF_XRB 2621440
#define OFF_RSI 4718592
#define OFF_WQV 4751360
#define OFF_WTB 4761600
#define OFF_FA  4769792
#define OFF_FB  4769920

// K0: cast weights to bf16 + fold BN constants
__global__ void k_wprep(const float* __restrict__ wq, const float* __restrict__ wv,
        const float* __restrict__ wt, const float* __restrict__ bt,
        const float* __restrict__ gamma, const float* __restrict__ beta,
        const float* __restrict__ bn_mean, const float* __restrict__ bn_var,
        ushort* __restrict__ wqvb, ushort* __restrict__ wtb,
        float* __restrict__ fA, float* __restrict__ fB) {
    int idx = blockIdx.x * 256 + threadIdx.x;
    if (idx < 4096) wqvb[idx] = f2b(wq[idx]);
    else if (idx < 20480) wqvb[idx] = f2b(wv[idx - 4096]);
    else if (idx < 36864) wtb[idx - 20480] = f2b(wt[idx - 20480]);
    else if (idx < 36992) {
        int c = idx - 36864;
        float A = gamma[c] * rsqrtf(bn_var[c] + 1e-5f);
        fA[c] = A;
        fB[c] = (bt[c] - bn_mean[c]) * A + beta[c];
    }
}

// K1: MFMA projection. Qt[b,n,d] (d<32), Vb[b,d,n] = wv.x + bv. Weights in LDS.
__global__ __launch_bounds__(256) void k_proj(const float* __restrict__ x,
        const ushort* __restrict__ wqvb, const float* __restrict__ bv,
        ushort* __restrict__ Qt, ushort* __restrict__ Vb) {
    __shared__ ushort Wl[160][136];
    __shared__ ushort Xs[64][136];   // [n][c] bf16
    int b  = blockIdx.x >> 5;
    int n0 = (blockIdx.x & 31) << 6;
    int tid = threadIdx.x;
    // stage weights: 2560 b128 chunks
    #pragma unroll
    for (int k = 0; k < 10; ++k) {
        int idx = k * 256 + tid;
        int r = idx >> 4, c = idx & 15;
        *(uint4*)&Wl[r][c * 8] = *(const uint4*)&wqvb[r * 128 + c * 8];
    }
    const float* xb = x + (size_t)b * CC * NN;
    for (int idx = tid; idx < 2048; idx += 256) {
        int c = idx >> 4, n4 = (idx & 15) << 2;
        float4 xv = *(const float4*)&xb[c * NN + n0 + n4];
        Xs[n4][c]     = f2b(xv.x);
        Xs[n4 + 1][c] = f2b(xv.y);
        Xs[n4 + 2][c] = f2b(xv.z);
        Xs[n4 + 3][c] = f2b(xv.w);
    }
    __syncthreads();
    int w = tid >> 6, l = tid & 63, lr = l & 15, lg = l >> 4;
    f32x4 zero = {0.f, 0.f, 0.f, 0.f};
    int nn = n0 + w * 16 + lr;
    for (int dt = 0; dt < 10; ++dt) {
        f32x4 acc = zero;
        #pragma unroll
        for (int k = 0; k < 4; ++k) {
            bf16x8 a  = *(const bf16x8*)&Wl[dt * 16 + lr][k * 32 + lg * 8];
            bf16x8 bx = *(const bf16x8*)&Xs[w * 16 + lr][k * 32 + lg * 8];
            acc = __builtin_amdgcn_mfma_f32_16x16x32_bf16(a, bx, acc, 0, 0, 0);
        }
        if (dt < 2) {
            ushort4 p = make_ushort4(f2b(acc[0]), f2b(acc[1]), f2b(acc[2]), f2b(acc[3]));
            *(ushort4*)&Qt[(size_t)(b * NN + nn) * CQ + dt * 16 + lg * 4] = p;
        } else {
            #pragma unroll
            for (int i = 0; i < 4; ++i) {
                int vd = (dt - 2) * 16 + lg * 4 + i;
                Vb[(size_t)(b * CC + vd) * NN + nn] = f2b(acc[i] + bv[vd]);
            }
        }
    }
}

// K2: row softmax denominators (no max-subtract; E bounded). RSI = 1/rowsum.
__global__ __launch_bounds__(256) void k_rowstats(const ushort* __restrict__ Qt,
        float* __restrict__ RSI) {
    __shared__ ushort Qm[128][40];
    int b  = blockIdx.x >> 5;
    int n0 = (blockIdx.x & 31) << 6;
    int tid = threadIdx.x;
    int w = tid >> 6, l = tid & 63, lr = l & 15, lg = l >> 4;
    const ushort* Qtb = Qt + (size_t)b * NN * CQ;
    bf16x8 aq = *(const bf16x8*)&Qtb[(size_t)(n0 + w * 16 + lr) * CQ + lg * 8];
    int i0 = tid * 2, i1 = tid * 2 + 1;
    int r0 = i0 >> 2, c0 = i0 & 3, r1 = i1 >> 2, c1 = i1 & 3;
    uint4 q0 = *(const uint4*)&Qtb[(size_t)(0 + r0) * CQ + c0 * 8];
    uint4 q1 = *(const uint4*)&Qtb[(size_t)(0 + r1) * CQ + c1 * 8];
    float S[4] = {0.f, 0.f, 0.f, 0.f};
    f32x4 zero = {0.f, 0.f, 0.f, 0.f};
    for (int t = 0; t < 16; ++t) {
        __syncthreads();
        *(uint4*)&Qm[r0][c0 * 8] = q0;
        *(uint4*)&Qm[r1][c1 * 8] = q1;
        __syncthreads();
        if (t < 15) {
            int mt = (t + 1) * 128;
            q0 = *(const uint4*)&Qtb[(size_t)(mt + r0) * CQ + c0 * 8];
            q1 = *(const uint4*)&Qtb[(size_t)(mt + r1) * CQ + c1 * 8];
        }
        #pragma unroll
        for (int mi = 0; mi < 8; ++mi) {
            bf16x8 bq = *(const bf16x8*)&Qm[mi * 16 + lr][lg * 8];
            f32x4 e = __builtin_amdgcn_mfma_f32_16x16x32_bf16(aq, bq, zero, 0, 0, 0);
            S[0] += __expf(e[0]); S[1] += __expf(e[1]);
            S[2] += __expf(e[2]); S[3] += __expf(e[3]);
        }
    }
    #pragma unroll
    for (int d = 1; d < 16; d <<= 1) {
        #pragma unroll
        for (int i = 0; i < 4; ++i) S[i] += __shfl_xor(S[i], d);
    }
    if (lr == 0) {
        #pragma unroll
        for (int i = 0; i < 4; ++i)
            RSI[b * NN + n0 + w * 16 + lg * 4 + i] = 1.f / S[i];
    }
}

// K3: attn + PV. 512 thr. E(16x16): Qm frags in regs, Qn frag from global.
// PV(32x32x16): wave quadrant (d-strip w>>1, m-half w&1). NT=128, T14 prefetch.
__global__ __launch_bounds__(512, 4) void k_attn_pv(const ushort* __restrict__ Qt,
        const ushort* __restrict__ Vb, const float* __restrict__ RSI,
        ushort* __restrict__ XRb) {
    __shared__ ushort Vs[128][136];  // [d][n]
    __shared__ ushort Ws[64][136];   // [m][n]
    __shared__ float rsi_s[128];
    __shared__ float csred[8][64];
    __shared__ float csum[64];
    int b  = blockIdx.x >> 5;
    int m0 = (blockIdx.x & 31) << 6;
    int tid = threadIdx.x;
    int w = tid >> 6, l = tid & 63, lr = l & 15, lg = l >> 4;
    const ushort* Qtb = Qt + (size_t)b * NN * CQ;
    const ushort* Vbb = Vb + (size_t)b * CC * NN;
    // E B-frags (block-constant m-tile)
    bf16x8 bm[4];
    #pragma unroll
    for (int mi = 0; mi < 4; ++mi)
        bm[mi] = *(const bf16x8*)&Qtb[(size_t)(m0 + mi * 16 + lr) * CQ + lg * 8];
    // tile-0 prefetch
    int dv = tid & 127, hv = tid >> 7;
    uint4 vreg[4];
    #pragma unroll
    for (int j = 0; j < 4; ++j)
        vreg[j] = *(const uint4*)&Vbb[(size_t)dv * NN + hv * 32 + j * 8];
    float rreg = (tid < 128) ? RSI[b * NN + tid] : 0.f;
    uint4 aqn = *(const uint4*)&Qtb[(size_t)(w * 16 + lr) * CQ + lg * 8];
    f32x4 zero = {0.f, 0.f, 0.f, 0.f};
    f32x16 pacc;
    #pragma unroll
    for (int r = 0; r < 16; ++r) pacc[r] = 0.f;
    float cs[4] = {0.f, 0.f, 0.f, 0.f};
    int ar = l & 31, kh = l >> 5;
    int dq = w >> 1, mq = w & 1;
    for (int t = 0; t < 16; ++t) {
        __syncthreads();                     // (a) prev PV done with Vs/Ws
        #pragma unroll
        for (int j = 0; j < 4; ++j)
            *(uint4*)&Vs[dv][hv * 32 + j * 8] = vreg[j];
        if (tid < 128) rsi_s[tid] = rreg;
        bf16x8 aq = as_b8(aqn);
        __syncthreads();                     // (b) LDS tile ready
        if (t < 15) {
            int nn2 = (t + 1) * 128;
            #pragma unroll
            for (int j = 0; j < 4; ++j)
                vreg[j] = *(const uint4*)&Vbb[(size_t)dv * NN + nn2 + hv * 32 + j * 8];
            if (tid < 128) rreg = RSI[b * NN + nn2 + tid];
            aqn = *(const uint4*)&Qtb[(size_t)(nn2 + w * 16 + lr) * CQ + lg * 8];
        }
        // ---- E phase (16x16), n-strip w ----
        __builtin_amdgcn_s_setprio(1);
        f32x4 e[4];
        #pragma unroll
        for (int mi = 0; mi < 4; ++mi)
            e[mi] = __builtin_amdgcn_mfma_f32_16x16x32_bf16(aq, bm[mi], zero, 0, 0, 0);
        __builtin_amdgcn_s_setprio(0);
        int nb = w * 16 + lg * 4;
        float r0 = rsi_s[nb], r1 = rsi_s[nb + 1], r2 = rsi_s[nb + 2], r3 = rsi_s[nb + 3];
        #pragma unroll
        for (int mi = 0; mi < 4; ++mi) {
            float w0 = __expf(e[mi][0]) * r0;
            float w1 = __expf(e[mi][1]) * r1;
            float w2 = __expf(e[mi][2]) * r2;
            float w3 = __expf(e[mi][3]) * r3;
            cs[mi] += w0 + w1 + w2 + w3;
            *(ushort4*)&Ws[mi * 16 + lr][nb] =
                make_ushort4(f2b(w0), f2b(w1), f2b(w2), f2b(w3));
        }
        __syncthreads();                     // (c) Ws ready
        // ---- PV (32x32x16): quadrant (dq, mq) ----
        __builtin_amdgcn_s_setprio(1);
        #pragma unroll
        for (int kk = 0; kk < 8; ++kk) {
            bf16x8 va = as_b8(*(const uint4*)&Vs[dq * 32 + ar][kk * 16 + kh * 8]);
            bf16x8 wb = as_b8(*(const uint4*)&Ws[mq * 32 + ar][kk * 16 + kh * 8]);
            pacc = __builtin_amdgcn_mfma_f32_32x32x16_bf16(va, wb, pacc, 0, 0, 0);
        }
        __builtin_amdgcn_s_setprio(0);
    }
    // column sums: reduce over lg (shfl), then over 8 waves (LDS)
    #pragma unroll
    for (int mi = 0; mi < 4; ++mi) {
        cs[mi] += __shfl_xor(cs[mi], 16);
        cs[mi] += __shfl_xor(cs[mi], 32);
    }
    if (lg == 0) {
        #pragma unroll
        for (int mi = 0; mi < 4; ++mi) csred[w][mi * 16 + lr] = cs[mi];
    }
    __syncthreads();
    if (tid < 64) {
        float tot = 0.f;
        #pragma unroll
        for (int w2 = 0; w2 < 8; ++w2) tot += csred[w2][tid];
        csum[tid] = 1.f / (1e-9f + tot);
    }
    __syncthreads();
    float inv = csum[mq * 32 + ar];
    int m = m0 + mq * 32 + ar;
    #pragma unroll
    for (int r = 0; r < 16; ++r) {
        int d = dq * 32 + (r & 3) + 8 * (r >> 2) + 4 * kh;
        XRb[(size_t)(b * CC + d) * NN + m] = f2b(pacc[r] * inv);
    }
}

// K4: MFMA final: t = wtb @ (x - XR); out = x + relu(t*fA + fB). Weights in LDS.
__global__ __launch_bounds__(256) void k_final(const float* __restrict__ x,
        const ushort* __restrict__ XRb, const ushort* __restrict__ wtb,
        const float* __restrict__ fA, const float* __restrict__ fB,
        float* __restrict__ out) {
    __shared__ ushort Wl[128][136];
    __shared__ ushort Us[64][136];   // [n][c] bf16
    int b  = blockIdx.x >> 5;
    int n0 = (blockIdx.x & 31) << 6;
    int tid = threadIdx.x;
    #pragma unroll
    for (int k = 0; k < 8; ++k) {
        int idx = k * 256 + tid;
        int r = idx >> 4, c = idx & 15;
        *(uint4*)&Wl[r][c * 8] = *(const uint4*)&wtb[r * 128 + c * 8];
    }
    const float*  xb  = x   + (size_t)b * CC * NN;
    const ushort* xrb = XRb + (size_t)b * CC * NN;
    for (int idx = tid; idx < 2048; idx += 256) {
        int c = idx >> 4, n4 = (idx & 15) << 2;
        float4 xv = *(const float4*)&xb[c * NN + n0 + n4];
        ushort4 rv = *(const ushort4*)&xrb[c * NN + n0 + n4];
        Us[n4][c]     = f2b(xv.x - b2f(rv.x));
        Us[n4 + 1][c] = f2b(xv.y - b2f(rv.y));
        Us[n4 + 2][c] = f2b(xv.z - b2f(rv.z));
        Us[n4 + 3][c] = f2b(xv.w - b2f(rv.w));
    }
    __syncthreads();
    int w = tid >> 6, l = tid & 63, lr = l & 15, lg = l >> 4;
    f32x4 zero = {0.f, 0.f, 0.f, 0.f};
    int nn = n0 + w * 16 + lr;
    for (int dt = 0; dt < 8; ++dt) {
        f32x4 acc = zero;
        #pragma unroll
        for (int k = 0; k < 4; ++k) {
            bf16x8 a  = *(const bf16x8*)&Wl[dt * 16 + lr][k * 32 + lg * 8];
            bf16x8 bx = *(const bf16x8*)&Us[w * 16 + lr][k * 32 + lg * 8];
            acc = __builtin_amdgcn_mfma_f32_16x16x32_bf16(a, bx, acc, 0, 0, 0);
        }
        #pragma unroll
        for (int i = 0; i < 4; ++i) {
            int r = dt * 16 + lg * 4 + i;
            float t = acc[i] * fA[r] + fB[r];
            t = fmaxf(t, 0.f);
            out[(size_t)(b * CC + r) * NN + nn] = xb[r * NN + nn] + t;
        }
    }
}

extern "C" void kernel_launch(void* const* d_in, const int* in_sizes, int n_in,
                              void* d_out, int out_size, void* d_ws, size_t ws_size,
                              hipStream_t stream) {
    const float* x       = (const float*)d_in[0];
    const float* wq      = (const float*)d_in[1];
    const float* wv      = (const float*)d_in[2];
    const float* bv      = (const float*)d_in[3];
    const float* wt      = (const float*)d_in[4];
    const float* bt      = (const float*)d_in[5];
    const float* gamma   = (const float*)d_in[6];
    const float* beta    = (const float*)d_in[7];
    const float* bn_mean = (const float*)d_in[8];
    const float* bn_var  = (const float*)d_in[9];
    float* out = (float*)d_out;
    float* ws  = (float*)d_ws;

    ushort* Qt   = (ushort*)ws;
    ushort* Vbp  = (ushort*)(ws + OFF_VB);
    ushort* XRb  = (ushort*)(ws + OFF_XRB);
    float*  RSI  = ws + OFF_RSI;
    ushort* WQV  = (ushort*)(ws + OFF_WQV);
    ushort* WTB  = (ushort*)(ws + OFF_WTB);
    float*  FA   = ws + OFF_FA;
    float*  FB   = ws + OFF_FB;

    k_wprep<<<145, 256, 0, stream>>>(wq, wv, wt, bt, gamma, beta, bn_mean, bn_var,
                                     WQV, WTB, FA, FB);
    k_proj<<<BB * 32, 256, 0, stream>>>(x, WQV, bv, Qt, Vbp);
    k_rowstats<<<BB * 32, 256, 0, stream>>>(Qt, RSI);
    k_attn_pv<<<BB * 32, 512, 0, stream>>>(Qt, Vbp, RSI, XRb);
    k_final<<<BB * 32, 256, 0, stream>>>(x, XRb, WTB, FA, FB, out);
}

// Round 6
// 85.953 us; speedup vs baseline: 1.5973x; 1.5973x over previous
//
#include <hip/hip_runtime.h>
#include <hip/hip_bf16.h>
#include <math.h>

#define BB 16
#define CC 128
#define NN 2048
#define CQ 32   // C/4

typedef __attribute__((ext_vector_type(8))) short bf16x8;
typedef __attribute__((ext_vector_type(4))) float f32x4;

__device__ __forceinline__ ushort f2b(float f) {
    __hip_bfloat16 h = __float2bfloat16(f);
    return *reinterpret_cast<ushort*>(&h);
}
__device__ __forceinline__ float b2f(ushort u) {
    union { unsigned u; float f; } v; v.u = ((unsigned)u) << 16;
    return v.f;
}

// ---------------- workspace layout (float granularity offsets) ----------------
// Qt  : bf16 [B][N][32]   off 0          (524,288 fl)
// Vb  : bf16 [B][128][N]  off 524,288    (2,097,152 fl)
// XRb : bf16 [B][128][N]  off 2,621,440  (2,097,152 fl)
// RSI : f32  [B][N]       off 4,718,592  (32,768 fl)
// WQV : bf16 [160][128]   off 4,751,360  (10,240 fl)
// WTB : bf16 [128][128]   off 4,761,600  (8,192 fl)
// FA  : f32  [128]        off 4,769,792
// FB  : f32  [128]        off 4,769,920
#define OFF_VB  524288
#define OFF_XRB 2621440
#define OFF_RSI 4718592
#define OFF_WQV 4751360
#define OFF_WTB 4761600
#define OFF_FA  4769792
#define OFF_FB  4769920

// K0: cast weights to bf16 + fold BN constants
__global__ void k_wprep(const float* __restrict__ wq, const float* __restrict__ wv,
        const float* __restrict__ wt, const float* __restrict__ bt,
        const float* __restrict__ gamma, const float* __restrict__ beta,
        const float* __restrict__ bn_mean, const float* __restrict__ bn_var,
        ushort* __restrict__ wqvb, ushort* __restrict__ wtb,
        float* __restrict__ fA, float* __restrict__ fB) {
    int idx = blockIdx.x * 256 + threadIdx.x;
    if (idx < 4096) wqvb[idx] = f2b(wq[idx]);
    else if (idx < 20480) wqvb[idx] = f2b(wv[idx - 4096]);
    else if (idx < 36864) wtb[idx - 20480] = f2b(wt[idx - 20480]);
    else if (idx < 36992) {
        int c = idx - 36864;
        float A = gamma[c] * rsqrtf(bn_var[c] + 1e-5f);
        fA[c] = A;
        fB[c] = (bt[c] - bn_mean[c]) * A + beta[c];
    }
}

// K1: MFMA projection. Qt[b,n,d] (d<32), Vb[b,d,n] = wv.x + bv. Weights in LDS.
__global__ __launch_bounds__(256) void k_proj(const float* __restrict__ x,
        const ushort* __restrict__ wqvb, const float* __restrict__ bv,
        ushort* __restrict__ Qt, ushort* __restrict__ Vb) {
    __shared__ ushort Wl[160][136];
    __shared__ ushort Xs[64][136];   // [n][c] bf16
    int b  = blockIdx.x >> 5;
    int n0 = (blockIdx.x & 31) << 6;
    int tid = threadIdx.x;
    #pragma unroll
    for (int k = 0; k < 10; ++k) {
        int idx = k * 256 + tid;
        int r = idx >> 4, c = idx & 15;
        *(uint4*)&Wl[r][c * 8] = *(const uint4*)&wqvb[r * 128 + c * 8];
    }
    const float* xb = x + (size_t)b * CC * NN;
    for (int idx = tid; idx < 2048; idx += 256) {
        int c = idx >> 4, n4 = (idx & 15) << 2;
        float4 xv = *(const float4*)&xb[c * NN + n0 + n4];
        Xs[n4][c]     = f2b(xv.x);
        Xs[n4 + 1][c] = f2b(xv.y);
        Xs[n4 + 2][c] = f2b(xv.z);
        Xs[n4 + 3][c] = f2b(xv.w);
    }
    __syncthreads();
    int w = tid >> 6, l = tid & 63, lr = l & 15, lg = l >> 4;
    f32x4 zero = {0.f, 0.f, 0.f, 0.f};
    int nn = n0 + w * 16 + lr;
    for (int dt = 0; dt < 10; ++dt) {
        f32x4 acc = zero;
        #pragma unroll
        for (int k = 0; k < 4; ++k) {
            bf16x8 a  = *(const bf16x8*)&Wl[dt * 16 + lr][k * 32 + lg * 8];
            bf16x8 bx = *(const bf16x8*)&Xs[w * 16 + lr][k * 32 + lg * 8];
            acc = __builtin_amdgcn_mfma_f32_16x16x32_bf16(a, bx, acc, 0, 0, 0);
        }
        if (dt < 2) {
            ushort4 p = make_ushort4(f2b(acc[0]), f2b(acc[1]), f2b(acc[2]), f2b(acc[3]));
            *(ushort4*)&Qt[(size_t)(b * NN + nn) * CQ + dt * 16 + lg * 4] = p;
        } else {
            #pragma unroll
            for (int i = 0; i < 4; ++i) {
                int vd = (dt - 2) * 16 + lg * 4 + i;
                Vb[(size_t)(b * CC + vd) * NN + nn] = f2b(acc[i] + bv[vd]);
            }
        }
    }
}

// K2: row softmax denominators (no max-subtract; E bounded). RSI = 1/rowsum.
__global__ __launch_bounds__(256) void k_rowstats(const ushort* __restrict__ Qt,
        float* __restrict__ RSI) {
    __shared__ ushort Qm[128][40];
    int b  = blockIdx.x >> 5;
    int n0 = (blockIdx.x & 31) << 6;
    int tid = threadIdx.x;
    int w = tid >> 6, l = tid & 63, lr = l & 15, lg = l >> 4;
    const ushort* Qtb = Qt + (size_t)b * NN * CQ;
    bf16x8 aq = *(const bf16x8*)&Qtb[(size_t)(n0 + w * 16 + lr) * CQ + lg * 8];
    int i0 = tid * 2, i1 = tid * 2 + 1;
    int r0 = i0 >> 2, c0 = i0 & 3, r1 = i1 >> 2, c1 = i1 & 3;
    uint4 q0 = *(const uint4*)&Qtb[(size_t)r0 * CQ + c0 * 8];
    uint4 q1 = *(const uint4*)&Qtb[(size_t)r1 * CQ + c1 * 8];
    float S[4] = {0.f, 0.f, 0.f, 0.f};
    f32x4 zero = {0.f, 0.f, 0.f, 0.f};
    for (int t = 0; t < 16; ++t) {
        __syncthreads();
        *(uint4*)&Qm[r0][c0 * 8] = q0;
        *(uint4*)&Qm[r1][c1 * 8] = q1;
        __syncthreads();
        if (t < 15) {
            int mt = (t + 1) * 128;
            q0 = *(const uint4*)&Qtb[(size_t)(mt + r0) * CQ + c0 * 8];
            q1 = *(const uint4*)&Qtb[(size_t)(mt + r1) * CQ + c1 * 8];
        }
        #pragma unroll
        for (int mi = 0; mi < 8; ++mi) {
            bf16x8 bq = *(const bf16x8*)&Qm[mi * 16 + lr][lg * 8];
            f32x4 e = __builtin_amdgcn_mfma_f32_16x16x32_bf16(aq, bq, zero, 0, 0, 0);
            S[0] += __expf(e[0]); S[1] += __expf(e[1]);
            S[2] += __expf(e[2]); S[3] += __expf(e[3]);
        }
    }
    #pragma unroll
    for (int d = 1; d < 16; d <<= 1) {
        #pragma unroll
        for (int i = 0; i < 4; ++i) S[i] += __shfl_xor(S[i], d);
    }
    if (lr == 0) {
        #pragma unroll
        for (int i = 0; i < 4; ++i)
            RSI[b * NN + n0 + w * 16 + lg * 4 + i] = 1.f / S[i];
    }
}

// K3: attn + PV, 512 thr, NT=128. E: bm[4] in regs, aq from global (L2-hot).
// PV: 16x16x32, wave w owns d-strip [16w,16w+16), pacc[4] = 16 VGPRs.
__global__ __launch_bounds__(512, 2) void k_attn_pv(const ushort* __restrict__ Qt,
        const ushort* __restrict__ Vb, const float* __restrict__ RSI,
        ushort* __restrict__ XRb) {
    __shared__ ushort Vs[128][136];  // [d][n]
    __shared__ ushort Ws[64][136];   // [m][n]
    __shared__ float rsi_s[128];
    __shared__ float csred[8][64];
    __shared__ float csum[64];
    int b  = blockIdx.x >> 5;
    int m0 = (blockIdx.x & 31) << 6;
    int tid = threadIdx.x;
    int w = tid >> 6, l = tid & 63, lr = l & 15, lg = l >> 4;
    const ushort* Qtb = Qt + (size_t)b * NN * CQ;
    const ushort* Vbb = Vb + (size_t)b * CC * NN;
    // E B-fragments: the block-constant m-tile (64 rows)
    bf16x8 bm[4];
    #pragma unroll
    for (int mi = 0; mi < 4; ++mi)
        bm[mi] = *(const bf16x8*)&Qtb[(size_t)(m0 + mi * 16 + lr) * CQ + lg * 8];
    f32x4 zero = {0.f, 0.f, 0.f, 0.f};
    f32x4 pacc[4];
    #pragma unroll
    for (int mi = 0; mi < 4; ++mi) pacc[mi] = zero;
    float cs[4] = {0.f, 0.f, 0.f, 0.f};
    int dv = tid >> 2, hv = tid & 3;   // V staging: row dv, col-quarter hv (32 cols)
    for (int t = 0; t < 16; ++t) {
        int nt = t * 128;
        // issue aq early; in flight across barrier (a)
        bf16x8 aq = *(const bf16x8*)&Qtb[(size_t)(nt + w * 16 + lr) * CQ + lg * 8];
        __syncthreads();                     // (a) prev PV done with Vs/Ws
        {
            const ushort* src = Vbb + (size_t)dv * NN + nt + hv * 32;
            *(uint4*)&Vs[dv][hv * 32]      = *(const uint4*)src;
            *(uint4*)&Vs[dv][hv * 32 + 8]  = *(const uint4*)(src + 8);
            *(uint4*)&Vs[dv][hv * 32 + 16] = *(const uint4*)(src + 16);
            *(uint4*)&Vs[dv][hv * 32 + 24] = *(const uint4*)(src + 24);
        }
        if (tid < 128) rsi_s[tid] = RSI[b * NN + nt + tid];
        __syncthreads();                     // (b) tile ready
        // ---- E phase: wave w owns n-strip [16w,16w+16) of this 128-n tile ----
        __builtin_amdgcn_s_setprio(1);
        f32x4 e[4];
        #pragma unroll
        for (int mi = 0; mi < 4; ++mi)
            e[mi] = __builtin_amdgcn_mfma_f32_16x16x32_bf16(aq, bm[mi], zero, 0, 0, 0);
        __builtin_amdgcn_s_setprio(0);
        int nb = w * 16 + lg * 4;
        float r0 = rsi_s[nb], r1 = rsi_s[nb + 1], r2 = rsi_s[nb + 2], r3 = rsi_s[nb + 3];
        #pragma unroll
        for (int mi = 0; mi < 4; ++mi) {
            float w0 = __expf(e[mi][0]) * r0;
            float w1 = __expf(e[mi][1]) * r1;
            float w2 = __expf(e[mi][2]) * r2;
            float w3 = __expf(e[mi][3]) * r3;
            cs[mi] += w0 + w1 + w2 + w3;
            *(ushort4*)&Ws[mi * 16 + lr][nb] =
                make_ushort4(f2b(w0), f2b(w1), f2b(w2), f2b(w3));
        }
        __syncthreads();                     // (c) Ws ready
        // ---- PV: wave w owns d in [16w, 16w+16), K = 128 ----
        __builtin_amdgcn_s_setprio(1);
        #pragma unroll
        for (int kk = 0; kk < 4; ++kk) {
            bf16x8 va = *(bf16x8*)&Vs[w * 16 + lr][kk * 32 + lg * 8];
            #pragma unroll
            for (int mi = 0; mi < 4; ++mi) {
                bf16x8 wb = *(bf16x8*)&Ws[mi * 16 + lr][kk * 32 + lg * 8];
                pacc[mi] = __builtin_amdgcn_mfma_f32_16x16x32_bf16(va, wb, pacc[mi], 0, 0, 0);
            }
        }
        __builtin_amdgcn_s_setprio(0);
    }
    // column sums: reduce over lg (shfl), then over 8 waves (LDS)
    #pragma unroll
    for (int mi = 0; mi < 4; ++mi) {
        cs[mi] += __shfl_xor(cs[mi], 16);
        cs[mi] += __shfl_xor(cs[mi], 32);
    }
    if (lg == 0) {
        #pragma unroll
        for (int mi = 0; mi < 4; ++mi) csred[w][mi * 16 + lr] = cs[mi];
    }
    __syncthreads();
    if (tid < 64) {
        float tot = 0.f;
        #pragma unroll
        for (int w2 = 0; w2 < 8; ++w2) tot += csred[w2][tid];
        csum[tid] = 1.f / (1e-9f + tot);
    }
    __syncthreads();
    #pragma unroll
    for (int mi = 0; mi < 4; ++mi) {
        int ml = mi * 16 + lr;
        float inv = csum[ml];
        #pragma unroll
        for (int i = 0; i < 4; ++i) {
            int d = w * 16 + lg * 4 + i;
            XRb[(size_t)(b * CC + d) * NN + m0 + ml] = f2b(pacc[mi][i] * inv);
        }
    }
}

// K4: MFMA final: t = wtb @ (x - XR); out = x + relu(t*fA + fB). Weights in LDS.
__global__ __launch_bounds__(256) void k_final(const float* __restrict__ x,
        const ushort* __restrict__ XRb, const ushort* __restrict__ wtb,
        const float* __restrict__ fA, const float* __restrict__ fB,
        float* __restrict__ out) {
    __shared__ ushort Wl[128][136];
    __shared__ ushort Us[64][136];   // [n][c] bf16
    int b  = blockIdx.x >> 5;
    int n0 = (blockIdx.x & 31) << 6;
    int tid = threadIdx.x;
    #pragma unroll
    for (int k = 0; k < 8; ++k) {
        int idx = k * 256 + tid;
        int r = idx >> 4, c = idx & 15;
        *(uint4*)&Wl[r][c * 8] = *(const uint4*)&wtb[r * 128 + c * 8];
    }
    const float*  xb  = x   + (size_t)b * CC * NN;
    const ushort* xrb = XRb + (size_t)b * CC * NN;
    for (int idx = tid; idx < 2048; idx += 256) {
        int c = idx >> 4, n4 = (idx & 15) << 2;
        float4 xv = *(const float4*)&xb[c * NN + n0 + n4];
        ushort4 rv = *(const ushort4*)&xrb[c * NN + n0 + n4];
        Us[n4][c]     = f2b(xv.x - b2f(rv.x));
        Us[n4 + 1][c] = f2b(xv.y - b2f(rv.y));
        Us[n4 + 2][c] = f2b(xv.z - b2f(rv.z));
        Us[n4 + 3][c] = f2b(xv.w - b2f(rv.w));
    }
    __syncthreads();
    int w = tid >> 6, l = tid & 63, lr = l & 15, lg = l >> 4;
    f32x4 zero = {0.f, 0.f, 0.f, 0.f};
    int nn = n0 + w * 16 + lr;
    for (int dt = 0; dt < 8; ++dt) {
        f32x4 acc = zero;
        #pragma unroll
        for (int k = 0; k < 4; ++k) {
            bf16x8 a  = *(const bf16x8*)&Wl[dt * 16 + lr][k * 32 + lg * 8];
            bf16x8 bx = *(const bf16x8*)&Us[w * 16 + lr][k * 32 + lg * 8];
            acc = __builtin_amdgcn_mfma_f32_16x16x32_bf16(a, bx, acc, 0, 0, 0);
        }
        #pragma unroll
        for (int i = 0; i < 4; ++i) {
            int r = dt * 16 + lg * 4 + i;
            float t = acc[i] * fA[r] + fB[r];
            t = fmaxf(t, 0.f);
            out[(size_t)(b * CC + r) * NN + nn] = xb[r * NN + nn] + t;
        }
    }
}

extern "C" void kernel_launch(void* const* d_in, const int* in_sizes, int n_in,
                              void* d_out, int out_size, void* d_ws, size_t ws_size,
                              hipStream_t stream) {
    const float* x       = (const float*)d_in[0];
    const float* wq      = (const float*)d_in[1];
    const float* wv      = (const float*)d_in[2];
    const float* bv      = (const float*)d_in[3];
    const float* wt      = (const float*)d_in[4];
    const float* bt      = (const float*)d_in[5];
    const float* gamma   = (const float*)d_in[6];
    const float* beta    = (const float*)d_in[7];
    const float* bn_mean = (const float*)d_in[8];
    const float* bn_var  = (const float*)d_in[9];
    float* out = (float*)d_out;
    float* ws  = (float*)d_ws;

    ushort* Qt   = (ushort*)ws;
    ushort* Vbp  = (ushort*)(ws + OFF_VB);
    ushort* XRb  = (ushort*)(ws + OFF_XRB);
    float*  RSI  = ws + OFF_RSI;
    ushort* WQV  = (ushort*)(ws + OFF_WQV);
    ushort* WTB  = (ushort*)(ws + OFF_WTB);
    float*  FA   = ws + OFF_FA;
    float*  FB   = ws + OFF_FB;

    k_wprep<<<145, 256, 0, stream>>>(wq, wv, wt, bt, gamma, beta, bn_mean, bn_var,
                                     WQV, WTB, FA, FB);
    k_proj<<<BB * 32, 256, 0, stream>>>(x, WQV, bv, Qt, Vbp);
    k_rowstats<<<BB * 32, 256, 0, stream>>>(Qt, RSI);
    k_attn_pv<<<BB * 32, 512, 0, stream>>>(Qt, Vbp, RSI, XRb);
    k_final<<<BB * 32, 256, 0, stream>>>(x, XRb, WTB, FA, FB, out);
}